// Round 9
// baseline (915.976 us; speedup 1.0000x reference)
//
#include <hip/hip_runtime.h>

#define B_ 16
#define N_ 2048
#define M_ 2048
#define D_ 64
#define SCALE 0.125f

typedef short sv8 __attribute__((ext_vector_type(8)));
typedef short sv4 __attribute__((ext_vector_type(4)));
typedef float fv4 __attribute__((ext_vector_type(4)));

__device__ __forceinline__ short f2bf(float x) {
    union { float f; unsigned u; } a; a.f = x;
    unsigned r = a.u + 0x7FFFu + ((a.u >> 16) & 1u);
    return (short)(r >> 16);
}
__device__ __forceinline__ unsigned cvtpk(float lo, float hi) {
    unsigned r;
    asm("v_cvt_pk_bf16_f32 %0, %1, %2" : "=v"(r) : "v"(lo), "v"(hi));
    return r;
}
__device__ __forceinline__ float bflo(unsigned u) { return __uint_as_float(u << 16); }
__device__ __forceinline__ float bfhi(unsigned u) { return __uint_as_float(u & 0xffff0000u); }

__global__ void conv_bf16(const float* __restrict__ in, short* __restrict__ outb) {
    int i = (blockIdx.x * 256 + threadIdx.x) * 4;
    float4 f = *(const float4*)(in + i);
    uint2 o; o.x = cvtpk(f.x, f.y); o.y = cvtpk(f.z, f.w);
    *(uint2*)(outb + i) = o;
}

__global__ void conv_vt(const float* __restrict__ v, short* __restrict__ vt) {
    __shared__ short tile[64][65];
    int t = threadIdx.x;
    int b = blockIdx.x >> 5;
    int mt = (blockIdx.x & 31) << 6;
    for (int i = 0; i < 4; ++i) {
        int idx = i * 256 + t;
        int m = idx >> 4;
        int dq = (idx & 15) << 2;
        float4 f = *(const float4*)(v + ((size_t)(b * M_ + mt + m) * D_ + dq));
        tile[m][dq + 0] = f2bf(f.x); tile[m][dq + 1] = f2bf(f.y);
        tile[m][dq + 2] = f2bf(f.z); tile[m][dq + 3] = f2bf(f.w);
    }
    __syncthreads();
    for (int j = 0; j < 2; ++j) {
        int idx = j * 256 + t;
        int d = idx >> 3;
        int mq = (idx & 7) << 3;
        sv4 o0, o1;
        #pragma unroll
        for (int c = 0; c < 4; ++c) o0[c] = tile[mq + c][d];
        #pragma unroll
        for (int c = 0; c < 4; ++c) o1[c] = tile[mq + 4 + c][d];
        short* dst = vt + ((size_t)(b * D_ + d) * M_ + mt + mq);
        *(sv4*)(dst) = o0;
        *(sv4*)(dst + 4) = o1;
    }
}

// ---------- DIAGNOSTIC: exact attn store pattern, NT stores, x4 reps ----------
__global__ __launch_bounds__(256) void abl_store_nt(float* __restrict__ attnp) {
    const int tid = threadIdx.x;
    const int w = tid >> 6, lane = tid & 63;
    const int r = lane & 15, g = lane >> 4;
    const int b = blockIdx.x >> 5;
    const int nw = ((blockIdx.x & 31) << 6) + w * 16;
    for (int rep = 0; rep < 4; ++rep) {
        for (int m0 = 0; m0 < M_; m0 += 64) {
            #pragma unroll
            for (int t = 0; t < 4; ++t) {
                const int nr = t * 4 + g;
                float v = (float)(m0 + t + rep) * 1e-4f + (float)lane * 1e-6f;
                fv4 o; o[0] = v; o[1] = v + 1e-6f; o[2] = v + 2e-6f; o[3] = v + 3e-6f;
                __builtin_nontemporal_store(o,
                    (fv4*)(attnp + (size_t)(b * N_ + nw + nr) * M_ + m0 + r * 4));
            }
        }
    }
}

// ---------- DIAGNOSTIC: exact attn store pattern, NORMAL stores, x4 reps ----------
__global__ __launch_bounds__(256) void abl_store_nm(float* __restrict__ attnp) {
    const int tid = threadIdx.x;
    const int w = tid >> 6, lane = tid & 63;
    const int r = lane & 15, g = lane >> 4;
    const int b = blockIdx.x >> 5;
    const int nw = ((blockIdx.x & 31) << 6) + w * 16;
    for (int rep = 0; rep < 4; ++rep) {
        for (int m0 = 0; m0 < M_; m0 += 64) {
            #pragma unroll
            for (int t = 0; t < 4; ++t) {
                const int nr = t * 4 + g;
                float v = (float)(m0 + t + rep) * 1e-4f + (float)lane * 1e-6f;
                fv4 o; o[0] = v; o[1] = v + 1e-6f; o[2] = v + 2e-6f; o[3] = v + 3e-6f;
                *(fv4*)(attnp + (size_t)(b * N_ + nw + nr) * M_ + m0 + r * 4) = o;
            }
        }
    }
}

// ---------- DIAGNOSTIC: full kernel minus attn stores, x2 reps ----------
__global__ __launch_bounds__(256) void abl_compute(
    const short* __restrict__ Qb, const short* __restrict__ Kb,
    const short* __restrict__ Vt, float* __restrict__ outp)
{
    __shared__ short Pb[4][2][16][64];
    __shared__ float rinv_sh[4][16];

    const int tid = threadIdx.x;
    const int w = tid >> 6, lane = tid & 63;
    const int r = lane & 15, g = lane >> 4;
    const int b = blockIdx.x >> 5;
    const int n0 = (blockIdx.x & 31) << 6;
    const int nw = n0 + w * 16;

    const short* qbase = Qb + ((b * N_ + nw + r) * D_ + g * 8);
    sv8 q0 = *(const sv8*)(qbase);
    sv8 q1 = *(const sv8*)(qbase + 32);
    const short* kbb = Kb + (size_t)b * M_ * D_;
    const short* vbb = Vt + (size_t)b * D_ * M_;

    char* pbase = (char*)&Pb[w][0][0][0];
    int wb[4], ra[2];
    #pragma unroll
    for (int s = 0; s < 4; ++s)
        wb[s] = r * 128 + (((s * 2 + (g >> 1)) ^ (r & 7)) << 4) + ((g & 1) * 8);
    #pragma unroll
    for (int c = 0; c < 2; ++c)
        ra[c] = r * 128 + (((c * 4 + g) ^ (r & 7)) << 4);

    for (int rep = 0; rep < 2; ++rep) {
        float lsum = 0.f;
        for (int m0 = 0; m0 < M_; m0 += 64) {
            #pragma unroll
            for (int s = 0; s < 4; ++s) {
                const short* ka = kbb + (m0 + s * 16 + r) * D_ + g * 8;
                sv8 k0 = *(const sv8*)ka;
                sv8 k1 = *(const sv8*)(ka + 32);
                fv4 acc = {0.f, 0.f, 0.f, 0.f};
                acc = __builtin_amdgcn_mfma_f32_16x16x32_bf16(k0, q0, acc, 0, 0, 0);
                acc = __builtin_amdgcn_mfma_f32_16x16x32_bf16(k1, q1, acc, 0, 0, 0);
                lsum += __expf(acc[0] * SCALE) + __expf(acc[1] * SCALE)
                      + __expf(acc[2] * SCALE) + __expf(acc[3] * SCALE);
            }
        }
        lsum += __shfl_xor(lsum, 16, 64);
        lsum += __shfl_xor(lsum, 32, 64);
        if (g == 0) rinv_sh[w][r] = 1.f / lsum;

        fv4 ac0 = {0.f,0.f,0.f,0.f}, ac1 = {0.f,0.f,0.f,0.f};
        fv4 ac2 = {0.f,0.f,0.f,0.f}, ac3 = {0.f,0.f,0.f,0.f};
        int buf = 0;
        for (int m0 = 0; m0 < M_; m0 += 64, buf ^= 1) {
            char* pb = pbase + (buf << 11);
            #pragma unroll
            for (int s = 0; s < 4; ++s) {
                const short* ka = kbb + (m0 + s * 16 + r) * D_ + g * 8;
                sv8 k0 = *(const sv8*)ka;
                sv8 k1 = *(const sv8*)(ka + 32);
                fv4 acc = {0.f, 0.f, 0.f, 0.f};
                acc = __builtin_amdgcn_mfma_f32_16x16x32_bf16(k0, q0, acc, 0, 0, 0);
                acc = __builtin_amdgcn_mfma_f32_16x16x32_bf16(k1, q1, acc, 0, 0, 0);
                float p0 = __expf(acc[0] * SCALE), p1 = __expf(acc[1] * SCALE);
                float p2 = __expf(acc[2] * SCALE), p3 = __expf(acc[3] * SCALE);
                uint2 pk; pk.x = cvtpk(p0, p1); pk.y = cvtpk(p2, p3);
                *(uint2*)(pb + wb[s]) = pk;
            }
            // (attn stores removed)
            #pragma unroll
            for (int c = 0; c < 2; ++c) {
                sv8 pa = *(const sv8*)(pb + ra[c]);
                const short* vb0 = vbb + r * M_ + m0 + c * 32 + g * 8;
                ac0 = __builtin_amdgcn_mfma_f32_16x16x32_bf16(pa, *(const sv8*)(vb0),           ac0, 0, 0, 0);
                ac1 = __builtin_amdgcn_mfma_f32_16x16x32_bf16(pa, *(const sv8*)(vb0 + 16 * M_), ac1, 0, 0, 0);
                ac2 = __builtin_amdgcn_mfma_f32_16x16x32_bf16(pa, *(const sv8*)(vb0 + 32 * M_), ac2, 0, 0, 0);
                ac3 = __builtin_amdgcn_mfma_f32_16x16x32_bf16(pa, *(const sv8*)(vb0 + 48 * M_), ac3, 0, 0, 0);
            }
        }
        float* obase = outp + (size_t)(b * N_ + nw + g * 4) * D_ + r;
        #pragma unroll
        for (int reg = 0; reg < 4; ++reg) {
            float ri = rinv_sh[w][g * 4 + reg];
            __builtin_nontemporal_store(ac0[reg] * ri, obase + reg * D_);
            __builtin_nontemporal_store(ac1[reg] * ri, obase + reg * D_ + 16);
            __builtin_nontemporal_store(ac2[reg] * ri, obase + reg * D_ + 32);
            __builtin_nontemporal_store(ac3[reg] * ri, obase + reg * D_ + 48);
        }
    }
}

// ---------- REAL KERNEL (unchanged from R8, runs LAST) ----------
__global__ __launch_bounds__(256) void attn_fused(
    const short* __restrict__ Qb, const short* __restrict__ Kb,
    const short* __restrict__ Vt,
    float* __restrict__ outp, float* __restrict__ attnp)
{
    __shared__ short Pb[4][2][16][64];
    __shared__ float rinv_sh[4][16];

    const int tid = threadIdx.x;
    const int w = tid >> 6, lane = tid & 63;
    const int r = lane & 15, g = lane >> 4;
    const int b = blockIdx.x >> 5;
    const int n0 = (blockIdx.x & 31) << 6;
    const int nw = n0 + w * 16;

    const short* qbase = Qb + ((b * N_ + nw + r) * D_ + g * 8);
    sv8 q0 = *(const sv8*)(qbase);
    sv8 q1 = *(const sv8*)(qbase + 32);
    const short* kbb = Kb + (size_t)b * M_ * D_;
    const short* vbb = Vt + (size_t)b * D_ * M_;

    float lsum = 0.f;
    for (int m0 = 0; m0 < M_; m0 += 64) {
        #pragma unroll
        for (int s = 0; s < 4; ++s) {
            const short* ka = kbb + (m0 + s * 16 + r) * D_ + g * 8;
            sv8 k0 = *(const sv8*)ka;
            sv8 k1 = *(const sv8*)(ka + 32);
            fv4 acc = {0.f, 0.f, 0.f, 0.f};
            acc = __builtin_amdgcn_mfma_f32_16x16x32_bf16(k0, q0, acc, 0, 0, 0);
            acc = __builtin_amdgcn_mfma_f32_16x16x32_bf16(k1, q1, acc, 0, 0, 0);
            lsum += __expf(acc[0] * SCALE) + __expf(acc[1] * SCALE)
                  + __expf(acc[2] * SCALE) + __expf(acc[3] * SCALE);
        }
    }
    lsum += __shfl_xor(lsum, 16, 64);
    lsum += __shfl_xor(lsum, 32, 64);
    if (g == 0) rinv_sh[w][r] = 1.f / lsum;

    fv4 ac0 = {0.f,0.f,0.f,0.f}, ac1 = {0.f,0.f,0.f,0.f};
    fv4 ac2 = {0.f,0.f,0.f,0.f}, ac3 = {0.f,0.f,0.f,0.f};
    char* pbase = (char*)&Pb[w][0][0][0];
    int wb[4], ra[2];
    #pragma unroll
    for (int s = 0; s < 4; ++s)
        wb[s] = r * 128 + (((s * 2 + (g >> 1)) ^ (r & 7)) << 4) + ((g & 1) * 8);
    #pragma unroll
    for (int c = 0; c < 2; ++c)
        ra[c] = r * 128 + (((c * 4 + g) ^ (r & 7)) << 4);

    int buf = 0;
    for (int m0 = 0; m0 < M_; m0 += 64, buf ^= 1) {
        char* pb = pbase + (buf << 11);
        #pragma unroll
        for (int s = 0; s < 4; ++s) {
            const short* ka = kbb + (m0 + s * 16 + r) * D_ + g * 8;
            sv8 k0 = *(const sv8*)ka;
            sv8 k1 = *(const sv8*)(ka + 32);
            fv4 acc = {0.f, 0.f, 0.f, 0.f};
            acc = __builtin_amdgcn_mfma_f32_16x16x32_bf16(k0, q0, acc, 0, 0, 0);
            acc = __builtin_amdgcn_mfma_f32_16x16x32_bf16(k1, q1, acc, 0, 0, 0);
            float p0 = __expf(acc[0] * SCALE), p1 = __expf(acc[1] * SCALE);
            float p2 = __expf(acc[2] * SCALE), p3 = __expf(acc[3] * SCALE);
            uint2 pk; pk.x = cvtpk(p0, p1); pk.y = cvtpk(p2, p3);
            *(uint2*)(pb + wb[s]) = pk;
        }
        #pragma unroll
        for (int t = 0; t < 4; ++t) {
            const int nr = t * 4 + g;
            uint2 pv = *(const uint2*)(pb + nr * 128 + (((r >> 1) ^ (nr & 7)) << 4) + ((r & 1) * 8));
            float ri = rinv_sh[w][nr];
            fv4 o;
            o[0] = bflo(pv.x) * ri; o[1] = bfhi(pv.x) * ri;
            o[2] = bflo(pv.y) * ri; o[3] = bfhi(pv.y) * ri;
            __builtin_nontemporal_store(o,
                (fv4*)(attnp + (size_t)(b * N_ + nw + nr) * M_ + m0 + r * 4));
        }
        #pragma unroll
        for (int c = 0; c < 2; ++c) {
            sv8 pa = *(const sv8*)(pb + ra[c]);
            const short* vb0 = vbb + r * M_ + m0 + c * 32 + g * 8;
            ac0 = __builtin_amdgcn_mfma_f32_16x16x32_bf16(pa, *(const sv8*)(vb0),           ac0, 0, 0, 0);
            ac1 = __builtin_amdgcn_mfma_f32_16x16x32_bf16(pa, *(const sv8*)(vb0 + 16 * M_), ac1, 0, 0, 0);
            ac2 = __builtin_amdgcn_mfma_f32_16x16x32_bf16(pa, *(const sv8*)(vb0 + 32 * M_), ac2, 0, 0, 0);
            ac3 = __builtin_amdgcn_mfma_f32_16x16x32_bf16(pa, *(const sv8*)(vb0 + 48 * M_), ac3, 0, 0, 0);
        }
    }

    float* obase = outp + (size_t)(b * N_ + nw + g * 4) * D_ + r;
    #pragma unroll
    for (int reg = 0; reg < 4; ++reg) {
        float ri = rinv_sh[w][g * 4 + reg];
        __builtin_nontemporal_store(ac0[reg] * ri, obase + reg * D_);
        __builtin_nontemporal_store(ac1[reg] * ri, obase + reg * D_ + 16);
        __builtin_nontemporal_store(ac2[reg] * ri, obase + reg * D_ + 32);
        __builtin_nontemporal_store(ac3[reg] * ri, obase + reg * D_ + 48);
    }
}

extern "C" void kernel_launch(void* const* d_in, const int* in_sizes, int n_in,
                              void* d_out, int out_size, void* d_ws, size_t ws_size,
                              hipStream_t stream) {
    const float* q = (const float*)d_in[0];
    const float* k = (const float*)d_in[1];
    const float* v = (const float*)d_in[2];
    float* outp = (float*)d_out;
    float* attnp = outp + (size_t)B_ * N_ * D_;

    short* Qb = (short*)d_ws;
    short* Kb = Qb + (size_t)B_ * N_ * D_;
    short* Vt = Kb + (size_t)B_ * M_ * D_;

    conv_bf16<<<2048, 256, 0, stream>>>(q, Qb);
    conv_bf16<<<2048, 256, 0, stream>>>(k, Kb);
    conv_vt<<<512, 256, 0, stream>>>(v, Vt);

    // diagnostics (outputs overwritten by the real kernel below)
    abl_store_nt<<<512, 256, 0, stream>>>(attnp);
    abl_store_nm<<<512, 256, 0, stream>>>(attnp);
    abl_compute<<<512, 256, 0, stream>>>(Qb, Kb, Vt, outp);

    // real kernel last: produces the final correct out + attn
    attn_fused<<<512, 256, 0, stream>>>(Qb, Kb, Vt, outp, attnp);
}